// Round 12
// baseline (226.188 us; speedup 1.0000x reference)
//
#include <hip/hip_runtime.h>

#define NN 100000
#define NE 640000
#define DF 128
#define NH 32
#define CAP 32        // bucket capacity; Poisson(6.4) -> P(deg>32) ~ 1e-15
#define NBLK 512      // 2 blocks/CU x 256 CUs: co-residency guaranteed at VGPR<=256
#define NTILE 6250    // 100000/16 row-tiles, exact

typedef __attribute__((ext_vector_type(8))) short bf16x8;
typedef __attribute__((ext_vector_type(4))) float f32x4;

__device__ __forceinline__ unsigned short f2bf(float x) {
    union { float f; unsigned u; } c; c.f = x;
    unsigned r = c.u + 0x7fffu + ((c.u >> 16) & 1u);  // RNE
    return (unsigned short)(r >> 16);
}
__device__ __forceinline__ float bf2f(unsigned short b) {
    union { unsigned u; float f; } c; c.u = ((unsigned)b) << 16;
    return c.f;
}

// software grid barrier: arrive (device-scope atomic) + spin until target arrivals.
// Safe because all NBLK blocks are co-resident (see launch_bounds/NBLK math above).
__device__ __forceinline__ void grid_bar(int* bar, int target) {
    __syncthreads();
    if (threadIdx.x == 0) {
        __threadfence();                 // release: prior writes visible device-wide
        atomicAdd(bar, 1);
        while (atomicAdd(bar, 0) < target)
            __builtin_amdgcn_s_sleep(4);
        __threadfence();                 // acquire
    }
    __syncthreads();
}

// ---------------- init: blocks 0..97 zero cnt; block 98 packs W frags; block 99 zeroes bar ----------------
__global__ __launch_bounds__(256) void init_kernel(
    const float* __restrict__ W1_l, const float* __restrict__ W1_r,
    unsigned short* __restrict__ wfrag, int4* __restrict__ cnt4, int* __restrict__ bar)
{
    if (blockIdx.x < 98) {
        int i = blockIdx.x * 256 + threadIdx.x;
        if (i < NN / 4) cnt4[i] = make_int4(0, 0, 0, 0);
        return;
    }
    if (blockIdx.x == 99) {
        if (threadIdx.x < 4) bar[threadIdx.x] = 0;
        return;
    }
    const int t = threadIdx.x;
    for (int slot = t; slot < 1024; slot += 256) {   // (ks,nt,lane)
        int lane = slot & 63;
        int nt = (slot >> 6) & 3;
        int ks = slot >> 8;
        int n = nt * 16 + (lane & 15);
        const float* Wn = (n < 32) ? (W1_l + n) : (W1_r + (n - 32));
        unsigned short v[8];
#pragma unroll
        for (int i = 0; i < 8; i++) {
            int k = ks * 32 + ((i >> 2) << 4) + ((lane >> 4) << 2) + (i & 3);
            v[i] = f2bf(Wn[(size_t)k * 32]);
        }
        unsigned int u0 = (unsigned)v[0] | ((unsigned)v[1] << 16);
        unsigned int u1 = (unsigned)v[2] | ((unsigned)v[3] << 16);
        unsigned int u2 = (unsigned)v[4] | ((unsigned)v[5] << 16);
        unsigned int u3 = (unsigned)v[6] | ((unsigned)v[7] << 16);
        *(uint4*)&wfrag[(size_t)slot * 8] = make_uint4(u0, u1, u2, u3);
    }
}

// ---------------- fused: gemm+fill -> BAR -> agg1 -> BAR -> agg2 ----------------
__global__ __launch_bounds__(256, 2) void fused_kernel(
    const float* __restrict__ x, const int* __restrict__ src, const int* __restrict__ dst,
    const float* __restrict__ b1, const float* __restrict__ W2_l,
    const float* __restrict__ W2_r, const float* __restrict__ b2,
    float* __restrict__ out,
    const unsigned short* __restrict__ wfrag, unsigned short* __restrict__ xl_bf,
    unsigned short* __restrict__ xr_bf, float* __restrict__ h2l,
    float* __restrict__ hrp, int* __restrict__ cnt, int* __restrict__ esrc,
    int* __restrict__ bar)
{
    const int bid = blockIdx.x, tid = threadIdx.x;
    const int gtid = bid * 256 + tid;

    // ---------------- P1a: MFMA GEMM [xl_bf | xr_bf] = x @ [W1_l | W1_r] ----------------
    {
        const int lane = tid & 63;
        const int wslot = (bid << 2) + (tid >> 6);   // 2048 wave slots
        const int m = lane & 15, g = lane >> 4;

#define BLOAD(ks, nt) const bf16x8 b##ks##nt = *(const bf16x8*)&wfrag[(size_t)(((ks)*4 + (nt)) * 64 + lane) * 8];
        BLOAD(0,0) BLOAD(0,1) BLOAD(0,2) BLOAD(0,3)
        BLOAD(1,0) BLOAD(1,1) BLOAD(1,2) BLOAD(1,3)
        BLOAD(2,0) BLOAD(2,1) BLOAD(2,2) BLOAD(2,3)
        BLOAD(3,0) BLOAD(3,1) BLOAD(3,2) BLOAD(3,3)
#undef BLOAD

        for (int tile = wslot; tile < NTILE; tile += NBLK * 4) {
            const int row0 = tile << 4;
            const float* xp = x + (size_t)(row0 + m) * DF + g * 4;

            f32x4 acc0 = {0.f,0.f,0.f,0.f}, acc1 = {0.f,0.f,0.f,0.f};
            f32x4 acc2 = {0.f,0.f,0.f,0.f}, acc3 = {0.f,0.f,0.f,0.f};

#define KSTEP(ks) { \
            float4 fa = *(const float4*)(xp + (ks) * 32); \
            float4 fb = *(const float4*)(xp + (ks) * 32 + 16); \
            bf16x8 af; \
            af[0] = (short)f2bf(fa.x); af[1] = (short)f2bf(fa.y); \
            af[2] = (short)f2bf(fa.z); af[3] = (short)f2bf(fa.w); \
            af[4] = (short)f2bf(fb.x); af[5] = (short)f2bf(fb.y); \
            af[6] = (short)f2bf(fb.z); af[7] = (short)f2bf(fb.w); \
            acc0 = __builtin_amdgcn_mfma_f32_16x16x32_bf16(af, b##ks##0, acc0, 0, 0, 0); \
            acc1 = __builtin_amdgcn_mfma_f32_16x16x32_bf16(af, b##ks##1, acc1, 0, 0, 0); \
            acc2 = __builtin_amdgcn_mfma_f32_16x16x32_bf16(af, b##ks##2, acc2, 0, 0, 0); \
            acc3 = __builtin_amdgcn_mfma_f32_16x16x32_bf16(af, b##ks##3, acc3, 0, 0, 0); }
            KSTEP(0) KSTEP(1) KSTEP(2) KSTEP(3)
#undef KSTEP

            // C/D: col = lane&15 (output channel n), row = 4*(lane>>4) + r  [m89]
#define CSTORE(nt) { \
            int n = (nt) * 16 + m; \
_Pragma("unroll") \
            for (int r = 0; r < 4; r++) { \
                int rr = row0 + g * 4 + r; \
                unsigned short v = f2bf(acc##nt[r]); \
                if (n < 32) xl_bf[(size_t)rr * 32 + n] = v; \
                else        xr_bf[(size_t)rr * 32 + (n - 32)] = v; \
            } }
            CSTORE(0) CSTORE(1) CSTORE(2) CSTORE(3)
#undef CSTORE
        }
    }

    // ---------------- P1b: bucket fill ----------------
    for (int e = gtid; e < NE; e += NBLK * 256) {
        int d = dst[e];
        int p = atomicAdd(&cnt[d], 1);
        if (p < CAP) esrc[((size_t)d << 5) + p] = src[e];
    }

    grid_bar(bar, NBLK);

    // ---------------- P2: layer1 aggregate + relu + layer2 transforms ----------------
    {
        const int l = tid & 31;
        const int j = l >> 2;    // row slot 0..7
        const int c = l & 3;     // features 8c..8c+7
        const float4* b14 = (const float4*)&b1[c * 8];
        float4 bb0 = b14[0], bb1 = b14[1];
        const float4* wl4 = (const float4*)&W2_l[c * 8];
        float4 wl0 = wl4[0], wl1 = wl4[1];
        const float4* wr4 = (const float4*)&W2_r[c * 8];
        float4 wr0 = wr4[0], wr1 = wr4[1];
        const float bs[8]  = {bb0.x, bb0.y, bb0.z, bb0.w, bb1.x, bb1.y, bb1.z, bb1.w};
        const float wls[8] = {wl0.x, wl0.y, wl0.z, wl0.w, wl1.x, wl1.y, wl1.z, wl1.w};
        const float wrs[8] = {wr0.x, wr0.y, wr0.z, wr0.w, wr1.x, wr1.y, wr1.z, wr1.w};

        for (int node = bid * 8 + (tid >> 5); node < NN; node += NBLK * 8) {
            const int dg = cnt[node];
            const int lim = (dg < CAP) ? dg : CAP;
            const int* ep = esrc + ((size_t)node << 5);

            float acc[8];
#pragma unroll
            for (int i = 0; i < 8; i++) acc[i] = 0.f;

            for (int jb = 0; jb < lim; jb += 8) {
                int jj = jb + j;
                if (jj < lim) {
                    int s = ep[jj];
                    uint4 v = *(const uint4*)&xl_bf[(size_t)s * NH + c * 8];
#pragma unroll
                    for (int i = 0; i < 4; i++) {
                        unsigned u = (&v.x)[i];
                        acc[2 * i]     += bf2f((unsigned short)(u & 0xffffu));
                        acc[2 * i + 1] += bf2f((unsigned short)(u >> 16));
                    }
                }
            }
#pragma unroll
            for (int mm = 4; mm <= 16; mm <<= 1)
#pragma unroll
                for (int i = 0; i < 8; i++) acc[i] += __shfl_xor(acc[i], mm);

            const float inv = 1.0f / fmaxf((float)dg, 1.0f);
            uint4 xv = *(const uint4*)&xr_bf[(size_t)node * NH + c * 8];
            float sl = 0.f, sr = 0.f;
#pragma unroll
            for (int i = 0; i < 4; i++) {
                unsigned u = (&xv.x)[i];
                float xlo = bf2f((unsigned short)(u & 0xffffu));
                float xhi = bf2f((unsigned short)(u >> 16));
                float h0 = fmaxf(fmaf(acc[2 * i],     inv, xlo + bs[2 * i]),     0.f);
                float h1 = fmaxf(fmaf(acc[2 * i + 1], inv, xhi + bs[2 * i + 1]), 0.f);
                sl = fmaf(h0, wls[2 * i], sl); sl = fmaf(h1, wls[2 * i + 1], sl);
                sr = fmaf(h0, wrs[2 * i], sr); sr = fmaf(h1, wrs[2 * i + 1], sr);
            }
            sl += __shfl_xor(sl, 1); sl += __shfl_xor(sl, 2);
            sr += __shfl_xor(sr, 1); sr += __shfl_xor(sr, 2);
            if (l == 0) {
                h2l[node] = sl;
                hrp[node] = sr;
            }
        }
    }

    grid_bar(bar, 2 * NBLK);

    // ---------------- P3: layer2 aggregate + final ----------------
    {
        const float bias2 = b2[0];
        for (int i = gtid; i < NN; i += NBLK * 256) {
            int dg = cnt[i];
            int lim = (dg < CAP) ? dg : CAP;
            const int* ep = esrc + ((size_t)i << 5);
            float s0 = 0.f, s1 = 0.f, s2 = 0.f, s3 = 0.f;
            int jj = 0;
            for (; jj + 3 < lim; jj += 4) {
                int4 s = *(const int4*)&ep[jj];
                s0 += h2l[s.x];
                s1 += h2l[s.y];
                s2 += h2l[s.z];
                s3 += h2l[s.w];
            }
            for (; jj < lim; jj++) s0 += h2l[ep[jj]];
            out[i] = ((s0 + s1) + (s2 + s3)) / fmaxf((float)dg, 1.0f) + hrp[i] + bias2;
        }
    }
}

extern "C" void kernel_launch(void* const* d_in, const int* in_sizes, int n_in,
                              void* d_out, int out_size, void* d_ws, size_t ws_size,
                              hipStream_t stream)
{
    const float* x    = (const float*)d_in[0];
    const int*   ei   = (const int*)d_in[1];
    const float* W1_l = (const float*)d_in[2];
    const float* W1_r = (const float*)d_in[3];
    const float* b1   = (const float*)d_in[4];
    const float* W2_l = (const float*)d_in[5];
    const float* W2_r = (const float*)d_in[6];
    const float* b2   = (const float*)d_in[7];
    float* out = (float*)d_out;

    const int* src = ei;
    const int* dst = ei + NE;

    unsigned short* wfrag = (unsigned short*)d_ws;               // 16 KB
    unsigned short* xl_bf = wfrag + 8192;                        // NN*32 bf16 (6.4 MB)
    unsigned short* xr_bf = xl_bf + (size_t)NN * NH;             // NN*32 bf16 (6.4 MB)
    float* h2l      = (float*)(xr_bf + (size_t)NN * NH);         // NN f32
    float* hrp      = h2l + NN;                                  // NN f32
    int*   cnt      = (int*)(hrp + NN);                          // NN int
    int*   esrc     = cnt + NN;                                  // NN*CAP int (12.8 MB)
    int*   bar      = esrc + (size_t)NN * CAP;                   // 4 int (barrier state)

    init_kernel<<<100, 256, 0, stream>>>(W1_l, W1_r, wfrag, (int4*)cnt, bar);
    fused_kernel<<<NBLK, 256, 0, stream>>>(x, src, dst, b1, W2_l, W2_r, b2, out,
                                           wfrag, xl_bf, xr_bf, h2l, hrp, cnt, esrc, bar);
}

// Round 13
// 83.324 us; speedup vs baseline: 2.7146x; 2.7146x over previous
//
#include <hip/hip_runtime.h>

#define NN 100000
#define NE 640000
#define DF 128
#define NH 32
#define CAP 32        // bucket capacity; Poisson(6.4) -> P(deg>32) ~ 1e-15
#define NTILE 6250    // 100000/16 row-tiles, exact
#define GEMMB 1563    // ceil(NTILE/4)

typedef __attribute__((ext_vector_type(8))) short bf16x8;
typedef __attribute__((ext_vector_type(4))) float f32x4;

__device__ __forceinline__ unsigned short f2bf(float x) {
    union { float f; unsigned u; } c; c.f = x;
    unsigned r = c.u + 0x7fffu + ((c.u >> 16) & 1u);  // RNE
    return (unsigned short)(r >> 16);
}
__device__ __forceinline__ float bf2f(unsigned short b) {
    union { unsigned u; float f; } c; c.u = ((unsigned)b) << 16;
    return c.f;
}

// ---------------- gemm: zero cnt (leading threads) + LDS W-pack + MFMA ----------------
// [xl_bf | xr_bf] = x @ [W1_l | W1_r], one 16-row tile per wave.
__global__ __launch_bounds__(256) void gemm_kernel(
    const float* __restrict__ x, const float* __restrict__ W1_l,
    const float* __restrict__ W1_r, unsigned short* __restrict__ xl_bf,
    unsigned short* __restrict__ xr_bf, int4* __restrict__ cnt4)
{
    // zero cnt: first 25000 global threads (blocks 0..97)
    const int g0 = blockIdx.x * 256 + threadIdx.x;
    if (g0 < NN / 4) cnt4[g0] = make_int4(0, 0, 0, 0);

    // pack W fragments into LDS: slot s = (ks*4+nt)*64+lane, 8 bf16 each.
    // elem i of slot: col n = nt*16+(lane&15); k = ks*32 + 16*(i>>2) + 4*(lane>>4) + (i&3)
    __shared__ unsigned short wl[8192];  // 16 KB
    for (int s = threadIdx.x; s < 1024; s += 256) {
        int lane = s & 63;
        int nt = (s >> 6) & 3;
        int ks = s >> 8;
        int n = nt * 16 + (lane & 15);
        const float* Wc = (n < 32) ? (W1_l + n) : (W1_r + (n - 32));
        unsigned short v[8];
#pragma unroll
        for (int i = 0; i < 8; i++) {
            int k = ks * 32 + ((i >> 2) << 4) + ((lane >> 4) << 2) + (i & 3);
            v[i] = f2bf(Wc[(size_t)k * 32]);
        }
        unsigned u0 = (unsigned)v[0] | ((unsigned)v[1] << 16);
        unsigned u1 = (unsigned)v[2] | ((unsigned)v[3] << 16);
        unsigned u2 = (unsigned)v[4] | ((unsigned)v[5] << 16);
        unsigned u3 = (unsigned)v[6] | ((unsigned)v[7] << 16);
        *(uint4*)&wl[s * 8] = make_uint4(u0, u1, u2, u3);
    }
    __syncthreads();

    const int lane = threadIdx.x & 63;
    const int tile = (blockIdx.x << 2) + (threadIdx.x >> 6);
    if (tile >= NTILE) return;
    const int m = lane & 15, g = lane >> 4;
    const int row0 = tile << 4;

#define BLOAD(ks, nt) const bf16x8 b##ks##nt = *(const bf16x8*)&wl[(((ks)*4 + (nt)) * 64 + lane) * 8];
    BLOAD(0,0) BLOAD(0,1) BLOAD(0,2) BLOAD(0,3)
    BLOAD(1,0) BLOAD(1,1) BLOAD(1,2) BLOAD(1,3)
    BLOAD(2,0) BLOAD(2,1) BLOAD(2,2) BLOAD(2,3)
    BLOAD(3,0) BLOAD(3,1) BLOAD(3,2) BLOAD(3,3)
#undef BLOAD

    f32x4 acc0 = {0.f,0.f,0.f,0.f}, acc1 = {0.f,0.f,0.f,0.f};
    f32x4 acc2 = {0.f,0.f,0.f,0.f}, acc3 = {0.f,0.f,0.f,0.f};

    const float* xp = x + (size_t)(row0 + m) * DF + g * 4;

#define KSTEP(ks) { \
    float4 fa = *(const float4*)(xp + (ks) * 32); \
    float4 fb = *(const float4*)(xp + (ks) * 32 + 16); \
    bf16x8 af; \
    af[0] = (short)f2bf(fa.x); af[1] = (short)f2bf(fa.y); \
    af[2] = (short)f2bf(fa.z); af[3] = (short)f2bf(fa.w); \
    af[4] = (short)f2bf(fb.x); af[5] = (short)f2bf(fb.y); \
    af[6] = (short)f2bf(fb.z); af[7] = (short)f2bf(fb.w); \
    acc0 = __builtin_amdgcn_mfma_f32_16x16x32_bf16(af, b##ks##0, acc0, 0, 0, 0); \
    acc1 = __builtin_amdgcn_mfma_f32_16x16x32_bf16(af, b##ks##1, acc1, 0, 0, 0); \
    acc2 = __builtin_amdgcn_mfma_f32_16x16x32_bf16(af, b##ks##2, acc2, 0, 0, 0); \
    acc3 = __builtin_amdgcn_mfma_f32_16x16x32_bf16(af, b##ks##3, acc3, 0, 0, 0); }
    KSTEP(0) KSTEP(1) KSTEP(2) KSTEP(3)
#undef KSTEP

    // C/D: col = lane&15 (output channel n), row = 4*(lane>>4) + r  [m89]
#define CSTORE(nt) { \
    int n = (nt) * 16 + m; \
_Pragma("unroll") \
    for (int r = 0; r < 4; r++) { \
        int rr = row0 + g * 4 + r; \
        unsigned short v = f2bf(acc##nt[r]); \
        if (n < 32) xl_bf[(size_t)rr * 32 + n] = v; \
        else        xr_bf[(size_t)rr * 32 + (n - 32)] = v; \
    } }
    CSTORE(0) CSTORE(1) CSTORE(2) CSTORE(3)
#undef CSTORE
}

// ---------------- bucket fill: esrc[dst*CAP + p] = src ; cnt[dst] ends as degree ----------------
__global__ __launch_bounds__(256) void fill_kernel(const int* __restrict__ src,
                                                   const int* __restrict__ dst,
                                                   int* __restrict__ cnt,
                                                   int* __restrict__ esrc)
{
    int e = blockIdx.x * 256 + threadIdx.x;
    if (e < NE) {
        int d = dst[e];
        int p = atomicAdd(&cnt[d], 1);
        if (p < CAP) esrc[((size_t)d << 5) + p] = src[e];
    }
}

// ---------------- fused layer1 aggregate + relu + layer2 transforms ----------------
// 32 lanes per node: lane = (row j = l>>2, feature-chunk c = l&3); uint4 loads -> 8 lines in flight.
__global__ __launch_bounds__(256) void agg1_fused_kernel(
    const int* __restrict__ cnt, const int* __restrict__ esrc,
    const unsigned short* __restrict__ xl_bf,
    const unsigned short* __restrict__ xr_bf, const float* __restrict__ b1,
    const float* __restrict__ W2_l, const float* __restrict__ W2_r,
    float* __restrict__ h2l, float* __restrict__ hrp)
{
    const int node = blockIdx.x * 8 + (threadIdx.x >> 5);
    if (node >= NN) return;
    const int l = threadIdx.x & 31;
    const int j = l >> 2;    // row slot 0..7
    const int c = l & 3;     // features 8c..8c+7
    const int dg = cnt[node];
    const int lim = (dg < CAP) ? dg : CAP;
    const int* ep = esrc + ((size_t)node << 5);

    float acc[8];
#pragma unroll
    for (int i = 0; i < 8; i++) acc[i] = 0.f;

    for (int jb = 0; jb < lim; jb += 8) {
        int jj = jb + j;
        if (jj < lim) {
            int s = ep[jj];
            uint4 v = *(const uint4*)&xl_bf[(size_t)s * NH + c * 8];
#pragma unroll
            for (int i = 0; i < 4; i++) {
                unsigned u = (&v.x)[i];
                acc[2 * i]     += bf2f((unsigned short)(u & 0xffffu));
                acc[2 * i + 1] += bf2f((unsigned short)(u >> 16));
            }
        }
    }
#pragma unroll
    for (int mm = 4; mm <= 16; mm <<= 1)
#pragma unroll
        for (int i = 0; i < 8; i++) acc[i] += __shfl_xor(acc[i], mm);

    const float inv = 1.0f / fmaxf((float)dg, 1.0f);
    uint4 xv = *(const uint4*)&xr_bf[(size_t)node * NH + c * 8];
    float xs[8];
#pragma unroll
    for (int i = 0; i < 4; i++) {
        unsigned u = (&xv.x)[i];
        xs[2 * i]     = bf2f((unsigned short)(u & 0xffffu));
        xs[2 * i + 1] = bf2f((unsigned short)(u >> 16));
    }
    const float4* b14 = (const float4*)&b1[c * 8];
    float4 bb0 = b14[0], bb1 = b14[1];
    const float4* wl4 = (const float4*)&W2_l[c * 8];
    float4 wl0 = wl4[0], wl1 = wl4[1];
    const float4* wr4 = (const float4*)&W2_r[c * 8];
    float4 wr0 = wr4[0], wr1 = wr4[1];
    const float bs[8]  = {bb0.x, bb0.y, bb0.z, bb0.w, bb1.x, bb1.y, bb1.z, bb1.w};
    const float wls[8] = {wl0.x, wl0.y, wl0.z, wl0.w, wl1.x, wl1.y, wl1.z, wl1.w};
    const float wrs[8] = {wr0.x, wr0.y, wr0.z, wr0.w, wr1.x, wr1.y, wr1.z, wr1.w};

    float sl = 0.f, sr = 0.f;
#pragma unroll
    for (int i = 0; i < 8; i++) {
        float h = fmaxf(fmaf(acc[i], inv, xs[i] + bs[i]), 0.f);
        sl = fmaf(h, wls[i], sl);
        sr = fmaf(h, wrs[i], sr);
    }
    sl += __shfl_xor(sl, 1); sl += __shfl_xor(sl, 2);
    sr += __shfl_xor(sr, 1); sr += __shfl_xor(sr, 2);
    if (l == 0) {
        h2l[node] = sl;
        hrp[node] = sr;
    }
}

// ---------------- layer2 aggregate + final ----------------
__global__ __launch_bounds__(256) void agg2_final_kernel(
    const int* __restrict__ cnt, const int* __restrict__ esrc,
    const float* __restrict__ h2l, const float* __restrict__ hrp,
    const float* __restrict__ b2, float* __restrict__ out)
{
    int i = blockIdx.x * 256 + threadIdx.x;
    if (i >= NN) return;
    int dg = cnt[i];
    int lim = (dg < CAP) ? dg : CAP;
    const int* ep = esrc + ((size_t)i << 5);
    float s0 = 0.f, s1 = 0.f, s2 = 0.f, s3 = 0.f;
    int j = 0;
    for (; j + 3 < lim; j += 4) {
        int4 s = *(const int4*)&ep[j];
        s0 += h2l[s.x];
        s1 += h2l[s.y];
        s2 += h2l[s.z];
        s3 += h2l[s.w];
    }
    for (; j < lim; j++) s0 += h2l[ep[j]];
    out[i] = ((s0 + s1) + (s2 + s3)) / fmaxf((float)dg, 1.0f) + hrp[i] + b2[0];
}

extern "C" void kernel_launch(void* const* d_in, const int* in_sizes, int n_in,
                              void* d_out, int out_size, void* d_ws, size_t ws_size,
                              hipStream_t stream)
{
    const float* x    = (const float*)d_in[0];
    const int*   ei   = (const int*)d_in[1];
    const float* W1_l = (const float*)d_in[2];
    const float* W1_r = (const float*)d_in[3];
    const float* b1   = (const float*)d_in[4];
    const float* W2_l = (const float*)d_in[5];
    const float* W2_r = (const float*)d_in[6];
    const float* b2   = (const float*)d_in[7];
    float* out = (float*)d_out;

    const int* src = ei;
    const int* dst = ei + NE;

    unsigned short* xl_bf = (unsigned short*)d_ws;               // NN*32 bf16 (6.4 MB)
    unsigned short* xr_bf = xl_bf + (size_t)NN * NH;             // NN*32 bf16 (6.4 MB)
    float* h2l      = (float*)(xr_bf + (size_t)NN * NH);         // NN f32
    float* hrp      = h2l + NN;                                  // NN f32
    int*   cnt      = (int*)(hrp + NN);                          // NN int
    int*   esrc     = cnt + NN;                                  // NN*CAP int (12.8 MB)

    gemm_kernel<<<GEMMB, 256, 0, stream>>>(x, W1_l, W1_r, xl_bf, xr_bf, (int4*)cnt);
    fill_kernel<<<(NE + 255) / 256, 256, 0, stream>>>(src, dst, cnt, esrc);
    agg1_fused_kernel<<<(NN + 7) / 8, 256, 0, stream>>>(cnt, esrc, xl_bf, xr_bf,
                                                        b1, W2_l, W2_r, h2l, hrp);
    agg2_final_kernel<<<(NN + 255) / 256, 256, 0, stream>>>(cnt, esrc, h2l, hrp, b2, out);
}

// Round 14
// 71.218 us; speedup vs baseline: 3.1760x; 1.1700x over previous
//
#include <hip/hip_runtime.h>

#define NN 100000
#define NE 640000
#define DF 128
#define NH 32
#define CAP 32          // per-node bucket capacity in LDS (deg>32 ~ impossible)
#define BINS 1563       // ceil(NN/64): 64-node bins
#define BCAP 768        // slots per bin region (Poisson mean 409, +18 sigma)
#define HBLK 256        // edge-chunk blocks (hist & scatter use SAME mapping)
#define EPB 2500        // edges per chunk: 256*2500 = 640000 exact
#define NTILE 6250      // 100000/16 row-tiles, exact
#define GEMMB 1563      // ceil(NTILE/4)

typedef __attribute__((ext_vector_type(8))) short bf16x8;
typedef __attribute__((ext_vector_type(4))) float f32x4;

__device__ __forceinline__ unsigned short f2bf(float x) {
    union { float f; unsigned u; } c; c.f = x;
    unsigned r = c.u + 0x7fffu + ((c.u >> 16) & 1u);  // RNE
    return (unsigned short)(r >> 16);
}
__device__ __forceinline__ float bf2f(unsigned short b) {
    union { unsigned u; float f; } c; c.u = ((unsigned)b) << 16;
    return c.f;
}

// ---------------- D1: blocks [0,GEMMB) = MFMA GEMM; [GEMMB,GEMMB+HBLK) = edge hist ----------------
__global__ __launch_bounds__(256) void gemm_hist_kernel(
    const float* __restrict__ x, const float* __restrict__ W1_l,
    const float* __restrict__ W1_r, unsigned short* __restrict__ xl_bf,
    unsigned short* __restrict__ xr_bf, const int* __restrict__ dst,
    int* __restrict__ histmat)
{
    __shared__ unsigned short wl[8192];  // 16 KB (gemm: W frags; hist: reused as int[])

    if (blockIdx.x >= GEMMB) {
        // ---- histA: LDS histogram of dst>>6 over this chunk's 2500 edges ----
        int* lh = (int*)wl;
        const int h = blockIdx.x - GEMMB;
        for (int b = threadIdx.x; b < BINS; b += 256) lh[b] = 0;
        __syncthreads();
        const int e0 = h * EPB;
        for (int i = threadIdx.x; i < EPB; i += 256)
            atomicAdd(&lh[dst[e0 + i] >> 6], 1);
        __syncthreads();
        for (int b = threadIdx.x; b < BINS; b += 256)
            histmat[b * HBLK + h] = lh[b];
        return;
    }

    // ---- gemm: pack W fragments into LDS, then MFMA ----
    for (int s = threadIdx.x; s < 1024; s += 256) {
        int lane = s & 63;
        int nt = (s >> 6) & 3;
        int ks = s >> 8;
        int n = nt * 16 + (lane & 15);
        const float* Wc = (n < 32) ? (W1_l + n) : (W1_r + (n - 32));
        unsigned short v[8];
#pragma unroll
        for (int i = 0; i < 8; i++) {
            int k = ks * 32 + ((i >> 2) << 4) + ((lane >> 4) << 2) + (i & 3);
            v[i] = f2bf(Wc[(size_t)k * 32]);
        }
        unsigned u0 = (unsigned)v[0] | ((unsigned)v[1] << 16);
        unsigned u1 = (unsigned)v[2] | ((unsigned)v[3] << 16);
        unsigned u2 = (unsigned)v[4] | ((unsigned)v[5] << 16);
        unsigned u3 = (unsigned)v[6] | ((unsigned)v[7] << 16);
        *(uint4*)&wl[s * 8] = make_uint4(u0, u1, u2, u3);
    }
    __syncthreads();

    const int lane = threadIdx.x & 63;
    const int tile = (blockIdx.x << 2) + (threadIdx.x >> 6);
    if (tile >= NTILE) return;
    const int m = lane & 15, g = lane >> 4;
    const int row0 = tile << 4;

#define BLOAD(ks, nt) const bf16x8 b##ks##nt = *(const bf16x8*)&wl[(((ks)*4 + (nt)) * 64 + lane) * 8];
    BLOAD(0,0) BLOAD(0,1) BLOAD(0,2) BLOAD(0,3)
    BLOAD(1,0) BLOAD(1,1) BLOAD(1,2) BLOAD(1,3)
    BLOAD(2,0) BLOAD(2,1) BLOAD(2,2) BLOAD(2,3)
    BLOAD(3,0) BLOAD(3,1) BLOAD(3,2) BLOAD(3,3)
#undef BLOAD

    f32x4 acc0 = {0.f,0.f,0.f,0.f}, acc1 = {0.f,0.f,0.f,0.f};
    f32x4 acc2 = {0.f,0.f,0.f,0.f}, acc3 = {0.f,0.f,0.f,0.f};

    const float* xp = x + (size_t)(row0 + m) * DF + g * 4;

#define KSTEP(ks) { \
    float4 fa = *(const float4*)(xp + (ks) * 32); \
    float4 fb = *(const float4*)(xp + (ks) * 32 + 16); \
    bf16x8 af; \
    af[0] = (short)f2bf(fa.x); af[1] = (short)f2bf(fa.y); \
    af[2] = (short)f2bf(fa.z); af[3] = (short)f2bf(fa.w); \
    af[4] = (short)f2bf(fb.x); af[5] = (short)f2bf(fb.y); \
    af[6] = (short)f2bf(fb.z); af[7] = (short)f2bf(fb.w); \
    acc0 = __builtin_amdgcn_mfma_f32_16x16x32_bf16(af, b##ks##0, acc0, 0, 0, 0); \
    acc1 = __builtin_amdgcn_mfma_f32_16x16x32_bf16(af, b##ks##1, acc1, 0, 0, 0); \
    acc2 = __builtin_amdgcn_mfma_f32_16x16x32_bf16(af, b##ks##2, acc2, 0, 0, 0); \
    acc3 = __builtin_amdgcn_mfma_f32_16x16x32_bf16(af, b##ks##3, acc3, 0, 0, 0); }
    KSTEP(0) KSTEP(1) KSTEP(2) KSTEP(3)
#undef KSTEP

    // C/D: col = lane&15 (output channel n), row = 4*(lane>>4) + r  [m89]
#define CSTORE(nt) { \
    int n = (nt) * 16 + m; \
_Pragma("unroll") \
    for (int r = 0; r < 4; r++) { \
        int rr = row0 + g * 4 + r; \
        unsigned short v = f2bf(acc##nt[r]); \
        if (n < 32) xl_bf[(size_t)rr * 32 + n] = v; \
        else        xr_bf[(size_t)rr * 32 + (n - 32)] = v; \
    } }
    CSTORE(0) CSTORE(1) CSTORE(2) CSTORE(3)
#undef CSTORE
}

// ---------------- D2: per-bin exclusive scan over the 256 chunks ----------------
__global__ __launch_bounds__(256) void scan_kernel(const int* __restrict__ histmat,
                                                   int* __restrict__ startmat,
                                                   int* __restrict__ len)
{
    __shared__ int ls[256];
    const int j = blockIdx.x, t = threadIdx.x;
    int h = histmat[j * HBLK + t];
    ls[t] = h;
    __syncthreads();
    for (int off = 1; off < 256; off <<= 1) {
        int v = (t >= off) ? ls[t - off] : 0;
        __syncthreads();
        ls[t] += v;
        __syncthreads();
    }
    startmat[j * HBLK + t] = ls[t] - h;
    if (t == 255) len[j] = ls[255];
}

// ---------------- D3: scatter edges to bin regions (LDS ranks only, no global atomics) ----------------
__global__ __launch_bounds__(256) void scatter_kernel(const int* __restrict__ src,
                                                      const int* __restrict__ dst,
                                                      const int* __restrict__ startmat,
                                                      int* __restrict__ binned)
{
    __shared__ int lhist[BINS];
    const int h = blockIdx.x;
    for (int b = threadIdx.x; b < BINS; b += 256) lhist[b] = 0;
    __syncthreads();
    const int e0 = h * EPB;
    for (int i = threadIdx.x; i < EPB; i += 256) {
        int s = src[e0 + i], d = dst[e0 + i];
        int bin = d >> 6;
        int lr = atomicAdd(&lhist[bin], 1);   // LDS returning atomic: fast
        int pos = bin * BCAP + startmat[bin * HBLK + h] + lr;
        binned[pos] = (s << 6) | (d & 63);
    }
}

// ---------------- D4: per-bin bucket build (LDS) + layer1 agg + relu + layer2 dots ----------------
__global__ __launch_bounds__(256) void agg1_bin_kernel(
    const int* __restrict__ binned, const int* __restrict__ len,
    const unsigned short* __restrict__ xl_bf, const unsigned short* __restrict__ xr_bf,
    const float* __restrict__ b1, const float* __restrict__ W2_l,
    const float* __restrict__ W2_r, float* __restrict__ h2l, float* __restrict__ hrp)
{
    __shared__ int lcnt[64];
    __shared__ int lesrc[64 * CAP];   // 8 KB
    const int j = blockIdx.x, t = threadIdx.x;
    if (t < 64) lcnt[t] = 0;
    __syncthreads();
    const int L = len[j];
    const int* seg = binned + (size_t)j * BCAP;
    for (int i = t; i < L; i += 256) {
        int pk = seg[i];
        int dl = pk & 63, s = pk >> 6;
        int p = atomicAdd(&lcnt[dl], 1);
        if (p < CAP) lesrc[(dl << 5) + p] = s;
    }
    __syncthreads();

    const int l = t & 31, grp = t >> 5;   // 8 groups of 32 lanes
    const int j8 = l >> 2, c = l & 3;
    const float4* b14 = (const float4*)&b1[c * 8];
    float4 bb0 = b14[0], bb1 = b14[1];
    const float4* wl4 = (const float4*)&W2_l[c * 8];
    float4 wl0 = wl4[0], wl1 = wl4[1];
    const float4* wr4 = (const float4*)&W2_r[c * 8];
    float4 wr0 = wr4[0], wr1 = wr4[1];
    const float bs[8]  = {bb0.x, bb0.y, bb0.z, bb0.w, bb1.x, bb1.y, bb1.z, bb1.w};
    const float wls[8] = {wl0.x, wl0.y, wl0.z, wl0.w, wl1.x, wl1.y, wl1.z, wl1.w};
    const float wrs[8] = {wr0.x, wr0.y, wr0.z, wr0.w, wr1.x, wr1.y, wr1.z, wr1.w};

    for (int dl = grp; dl < 64; dl += 8) {
        const int node = j * 64 + dl;
        if (node >= NN) break;
        const int dg = lcnt[dl];
        const int lim = (dg < CAP) ? dg : CAP;

        float acc[8];
#pragma unroll
        for (int i = 0; i < 8; i++) acc[i] = 0.f;

        for (int jb = 0; jb < lim; jb += 8) {
            int jj = jb + j8;
            if (jj < lim) {
                int s = lesrc[(dl << 5) + jj];
                uint4 v = *(const uint4*)&xl_bf[(size_t)s * NH + c * 8];
#pragma unroll
                for (int i = 0; i < 4; i++) {
                    unsigned u = (&v.x)[i];
                    acc[2 * i]     += bf2f((unsigned short)(u & 0xffffu));
                    acc[2 * i + 1] += bf2f((unsigned short)(u >> 16));
                }
            }
        }
#pragma unroll
        for (int mm = 4; mm <= 16; mm <<= 1)
#pragma unroll
            for (int i = 0; i < 8; i++) acc[i] += __shfl_xor(acc[i], mm);

        const float inv = 1.0f / fmaxf((float)dg, 1.0f);
        uint4 xv = *(const uint4*)&xr_bf[(size_t)node * NH + c * 8];
        float sl = 0.f, sr = 0.f;
#pragma unroll
        for (int i = 0; i < 4; i++) {
            unsigned u = (&xv.x)[i];
            float xlo = bf2f((unsigned short)(u & 0xffffu));
            float xhi = bf2f((unsigned short)(u >> 16));
            float h0 = fmaxf(fmaf(acc[2 * i],     inv, xlo + bs[2 * i]),     0.f);
            float h1 = fmaxf(fmaf(acc[2 * i + 1], inv, xhi + bs[2 * i + 1]), 0.f);
            sl = fmaf(h0, wls[2 * i], sl); sl = fmaf(h1, wls[2 * i + 1], sl);
            sr = fmaf(h0, wrs[2 * i], sr); sr = fmaf(h1, wrs[2 * i + 1], sr);
        }
        sl += __shfl_xor(sl, 1); sl += __shfl_xor(sl, 2);
        sr += __shfl_xor(sr, 1); sr += __shfl_xor(sr, 2);
        if (l == 0) {
            h2l[node] = sl;
            hrp[node] = sr;
        }
    }
}

// ---------------- D5: per-bin layer2 aggregate via LDS float atomics + final ----------------
__global__ __launch_bounds__(256) void agg2_bin_kernel(
    const int* __restrict__ binned, const int* __restrict__ len,
    const float* __restrict__ h2l, const float* __restrict__ hrp,
    const float* __restrict__ b2, float* __restrict__ out)
{
    __shared__ float lsum[64];
    __shared__ int lcc[64];
    const int j = blockIdx.x, t = threadIdx.x;
    if (t < 64) { lsum[t] = 0.f; lcc[t] = 0; }
    __syncthreads();
    const int L = len[j];
    const int* seg = binned + (size_t)j * BCAP;
    for (int i = t; i < L; i += 256) {
        int pk = seg[i];
        int dl = pk & 63, s = pk >> 6;
        atomicAdd(&lsum[dl], h2l[s]);
        atomicAdd(&lcc[dl], 1);
    }
    __syncthreads();
    if (t < 64) {
        int node = j * 64 + t;
        if (node < NN)
            out[node] = lsum[t] / fmaxf((float)lcc[t], 1.0f) + hrp[node] + b2[0];
    }
}

extern "C" void kernel_launch(void* const* d_in, const int* in_sizes, int n_in,
                              void* d_out, int out_size, void* d_ws, size_t ws_size,
                              hipStream_t stream)
{
    const float* x    = (const float*)d_in[0];
    const int*   ei   = (const int*)d_in[1];
    const float* W1_l = (const float*)d_in[2];
    const float* W1_r = (const float*)d_in[3];
    const float* b1   = (const float*)d_in[4];
    const float* W2_l = (const float*)d_in[5];
    const float* W2_r = (const float*)d_in[6];
    const float* b2   = (const float*)d_in[7];
    float* out = (float*)d_out;

    const int* src = ei;
    const int* dst = ei + NE;

    unsigned short* xl_bf = (unsigned short*)d_ws;               // NN*32 bf16 (6.4 MB)
    unsigned short* xr_bf = xl_bf + (size_t)NN * NH;             // NN*32 bf16 (6.4 MB)
    float* h2l      = (float*)(xr_bf + (size_t)NN * NH);         // NN f32
    float* hrp      = h2l + NN;                                  // NN f32
    int*   histmat  = (int*)(hrp + NN);                          // BINS*256 (1.6 MB)
    int*   startmat = histmat + (size_t)BINS * HBLK;             // BINS*256 (1.6 MB)
    int*   len      = startmat + (size_t)BINS * HBLK;            // BINS
    int*   binned   = len + BINS;                                // BINS*BCAP (4.8 MB)

    gemm_hist_kernel<<<GEMMB + HBLK, 256, 0, stream>>>(x, W1_l, W1_r, xl_bf, xr_bf,
                                                       dst, histmat);
    scan_kernel<<<BINS, 256, 0, stream>>>(histmat, startmat, len);
    scatter_kernel<<<HBLK, 256, 0, stream>>>(src, dst, startmat, binned);
    agg1_bin_kernel<<<BINS, 256, 0, stream>>>(binned, len, xl_bf, xr_bf,
                                              b1, W2_l, W2_r, h2l, hrp);
    agg2_bin_kernel<<<BINS, 256, 0, stream>>>(binned, len, h2l, hrp, b2, out);
}